// Round 11
// baseline (597.796 us; speedup 1.0000x reference)
//
#include <hip/hip_runtime.h>

#define K_DIM 512
#define S_DIM 64
#define T_LEN 64
#define BW    16      // sequences per workgroup
#define NWG   32      // 32 workgroups x 16 seqs = 512

typedef float f32x4 __attribute__((ext_vector_type(4)));
typedef float f32x2 __attribute__((ext_vector_type(2)));
typedef short bf16x8 __attribute__((ext_vector_type(8)));

__device__ __forceinline__ short f2bf(float f) {
    unsigned u = __builtin_bit_cast(unsigned, f);
    u += 0x7fffu + ((u >> 16) & 1u);   // round-to-nearest-even
    return (short)(u >> 16);
}

// ---------------- pre-pass: bf16 A/Ceff + packed {pi, pi*Bt} pairs ----------------
__global__ void ssm_prep(const float* __restrict__ A, const float* __restrict__ B,
                         const float* __restrict__ C, const float* __restrict__ Pp,
                         short* __restrict__ A16, short* __restrict__ Ceff16,
                         f32x2* __restrict__ PPB) {
    int i = blockIdx.x * blockDim.x + threadIdx.x;
    int stride = gridDim.x * blockDim.x;
    for (int idx = i; idx < K_DIM * K_DIM; idx += stride)
        A16[idx] = f2bf(A[idx]);
    for (int idx = i; idx < S_DIM * K_DIM; idx += stride) {
        int s = idx >> 9;               // K_DIM == 512
        int k = idx & (K_DIM - 1);
        float p = 1.0f / (1.0f + expf(-Pp[idx]));
        Ceff16[idx] = f2bf(C[idx] * p);
        PPB[idx] = (f32x2){p, p * B[k * S_DIM + s]};   // {pi, pi*Bt[tok][k]}
    }
}

#define MFMA_(xa, fb, acc) acc = __builtin_amdgcn_mfma_f32_16x16x32_bf16(xa, fb, acc, 0, 0, 0)

// stream slice s (32-wide k-chunk, 4 nt-quarters) into block-scope SSA temps
#define LOADS4(s) \
    bf16x8 fa_##s = *(const bf16x8*)(aP0 + (s) * 32); \
    bf16x8 fb_##s = *(const bf16x8*)(aP1 + (s) * 32); \
    bf16x8 fc_##s = *(const bf16x8*)(aP2 + (s) * 32); \
    bf16x8 fd_##s = *(const bf16x8*)(aP3 + (s) * 32);

#define COMPS4(s) { \
    bf16x8 xa = *(const bf16x8*)&Xb[lr][(s) * 32 + 8 * lg]; \
    MFMA_(xa, fa_##s, acc0); MFMA_(xa, fb_##s, acc1); \
    MFMA_(xa, fc_##s, acc2); MFMA_(xa, fd_##s, acc3); }

// consume a slice held in the loop-carried prefetch vars
#define COMPC(va, vb, vc, vd, s) { \
    bf16x8 xa = *(const bf16x8*)&Xb[lr][(s) * 32 + 8 * lg]; \
    MFMA_(xa, va, acc0); MFMA_(xa, vb, acc1); \
    MFMA_(xa, vc, acc2); MFMA_(xa, vd, acc3); }

// reload the carried vars with slices 0,1 (same addresses every step)
#define PRE01() do { \
    fa0 = *(const bf16x8*)(aP0);      fb0 = *(const bf16x8*)(aP1); \
    fc0 = *(const bf16x8*)(aP2);      fd0 = *(const bf16x8*)(aP3); \
    fa1 = *(const bf16x8*)(aP0 + 32); fb1 = *(const bf16x8*)(aP1 + 32); \
    fc1 = *(const bf16x8*)(aP2 + 32); fd1 = *(const bf16x8*)(aP3 + 32); \
} while (0)

// raw barrier: drain LDS ops only; wave-private vmem loads ride across
#define LBAR asm volatile("s_waitcnt lgkmcnt(0)\ns_barrier" ::: "memory")

// ---------------- main: 32 WGs x 512 threads (8 waves), 16 seqs/WG, 64 steps ----------------
__global__ __launch_bounds__(512) __attribute__((amdgpu_waves_per_eu(2, 2)))
void ssm_main(
    const short* __restrict__ A16,     // [K][K] bf16 row-major
    const short* __restrict__ Ceff16,  // [S][K] bf16
    const f32x2* __restrict__ PPB,     // [S][K] {pi, pi*Bt}
    const float* __restrict__ init,    // [K]
    const int*   __restrict__ tokens,  // [BSZ][T]
    float*       __restrict__ out)     // [BSZ]
{
    __shared__ short Xb[BW][520];           // 16.6 KB bf16 state
    __shared__ short Cb[S_DIM][520];        // 66.6 KB Ceff (step-invariant, staged once)
    __shared__ float Lg[2][BW][68];         //  8.7 KB logits partials (2 K-halves)
    __shared__ int   tokS[BW][T_LEN];       //  4.1 KB   (total ~96 KB -> 1 WG/CU, 128-VGPR budget)

    const int tid = threadIdx.x;
    const int w  = tid >> 6;     // wave 0..7, owns k-range [w*64, w*64+64)
    const int l  = tid & 63;
    const int lg = l >> 4;
    const int lr = l & 15;
    const int b0 = blockIdx.x * BW;

    for (int idx = tid; idx < BW * T_LEN; idx += 512) {
        int r = idx >> 6, t = idx & 63;
        tokS[r][t] = tokens[(b0 + r) * T_LEN + t];
    }
    for (int idx = tid; idx < BW * K_DIM; idx += 512) {
        int r = idx >> 9, k = idx & (K_DIM - 1);
        Xb[r][k] = f2bf(init[k]);
    }
    for (int idx = tid; idx < (S_DIM * K_DIM) / 8; idx += 512) {
        int r = idx >> 6, c8 = (idx & 63) * 8;
        *(bf16x8*)&Cb[r][c8] = *(const bf16x8*)(Ceff16 + r * K_DIM + c8);
    }
    // fp32 master state: xm[nt][e] = x[seq=4*lg+e][k = w*64 + nt*16 + lr]
    float xm[4][4];
    #pragma unroll
    for (int nt = 0; nt < 4; ++nt) {
        float iv = init[w * 64 + nt * 16 + lr];
        #pragma unroll
        for (int e = 0; e < 4; ++e) xm[nt][e] = iv;
    }

    const int sq = w & 3;    // logits s-tile
    const int kh = w >> 2;   // logits K-half

    // per-lane A-fragment bases (one per nt-quarter of the wave's 64 rows)
    const short* aP0 = A16 + (w * 64 +      lr) * K_DIM + 8 * lg;
    const short* aP1 = A16 + (w * 64 + 16 + lr) * K_DIM + 8 * lg;
    const short* aP2 = A16 + (w * 64 + 32 + lr) * K_DIM + 8 * lg;
    const short* aP3 = A16 + (w * 64 + 48 + lr) * K_DIM + 8 * lg;

    // loop-carried prefetch of slices 0,1 (reloaded each step during P3)
    bf16x8 fa0, fb0, fc0, fd0, fa1, fb1, fc1, fd1;
    PRE01();

    float llacc = 0.0f;
    __syncthreads();

    for (int t = 0; t < T_LEN; ++t) {
        int mytok[4];
        #pragma unroll
        for (int e = 0; e < 4; ++e) mytok[e] = tokS[4 * lg + e][t];

        // ---- P1: logits partial GEMM (K-half kh), pure-LDS operands
        f32x4 lga = {0.f, 0.f, 0.f, 0.f};
        #pragma unroll
        for (int i = 0; i < 8; ++i) {
            bf16x8 xa = *(const bf16x8*)&Xb[lr][kh * 256 + i * 32 + 8 * lg];
            bf16x8 cb = *(const bf16x8*)&Cb[sq * 16 + lr][kh * 256 + i * 32 + 8 * lg];
            MFMA_(xa, cb, lga);
        }
        #pragma unroll
        for (int e = 0; e < 4; ++e)
            Lg[kh][4 * lg + e][sq * 16 + lr] = lga[e];

        // ---- P2: update GEMM, depth-2 stream (slices 0,1 already in carried regs)
        f32x4 acc0 = {0.f, 0.f, 0.f, 0.f};
        f32x4 acc1 = {0.f, 0.f, 0.f, 0.f};
        f32x4 acc2 = {0.f, 0.f, 0.f, 0.f};
        f32x4 acc3 = {0.f, 0.f, 0.f, 0.f};
        COMPC(fa0, fb0, fc0, fd0, 0)  LOADS4(2)
        COMPC(fa1, fb1, fc1, fd1, 1)  LOADS4(3)
        COMPS4(2)  LOADS4(4)
        COMPS4(3)  LOADS4(5)
        COMPS4(4)  LOADS4(6)
        COMPS4(5)  LOADS4(7)
        COMPS4(6)  LOADS4(8)
        COMPS4(7)  LOADS4(9)
        COMPS4(8)  LOADS4(10)
        COMPS4(9)  LOADS4(11)
        COMPS4(10) LOADS4(12)
        COMPS4(11) LOADS4(13)
        COMPS4(12) LOADS4(14)
        COMPS4(13) LOADS4(15)
        COMPS4(14)
        // ---- gating gathers: exactly 1 slice in flight here; fences stop hoisting
        __builtin_amdgcn_sched_barrier(0);
        f32x2 ppv[4][4];
        #pragma unroll
        for (int nt = 0; nt < 4; ++nt) {
            int k = w * 64 + nt * 16 + lr;
            #pragma unroll
            for (int e = 0; e < 4; ++e)
                ppv[nt][e] = PPB[mytok[e] * K_DIM + k];
        }
        __builtin_amdgcn_sched_barrier(0);
        COMPS4(15)
        LBAR;   // barrier1: Xb reads done, Lg visible (LDS-only exchange)

        // ---- P3: gating in fp32, rewrite Xb
        #pragma unroll
        for (int nt = 0; nt < 4; ++nt) {
            int k = w * 64 + nt * 16 + lr;
            #pragma unroll
            for (int e = 0; e < 4; ++e) {
                float a  = (nt == 0) ? acc0[e] : (nt == 1) ? acc1[e]
                         : (nt == 2) ? acc2[e] : acc3[e];
                float nx = xm[nt][e] + ppv[nt][e][0] * (a - xm[nt][e]) + ppv[nt][e][1];
                xm[nt][e] = nx;
                Xb[4 * lg + e][k] = f2bf(nx);
            }
        }
        // ---- prefetch next step's slices 0,1 (latency hides under softmax+barrier)
        PRE01();
        // waves 0..3: log-softmax + LL for 4 seqs each (16 lanes/seq, 4 logits/lane)
        if (w < 4) {
            int b = w * 4 + (l >> 4);
            int i = l & 15;
            float v[4];
            #pragma unroll
            for (int c = 0; c < 4; ++c)
                v[c] = Lg[0][b][i * 4 + c] + Lg[1][b][i * 4 + c];
            float m = fmaxf(fmaxf(v[0], v[1]), fmaxf(v[2], v[3]));
            m = fmaxf(m, __shfl_xor(m, 1));
            m = fmaxf(m, __shfl_xor(m, 2));
            m = fmaxf(m, __shfl_xor(m, 4));
            m = fmaxf(m, __shfl_xor(m, 8));
            float sum = expf(v[0] - m) + expf(v[1] - m) + expf(v[2] - m) + expf(v[3] - m);
            sum += __shfl_xor(sum, 1);
            sum += __shfl_xor(sum, 2);
            sum += __shfl_xor(sum, 4);
            sum += __shfl_xor(sum, 8);
            int tok = tokS[b][t];
            float sel = (i == (tok >> 2)) ? v[tok & 3] : 0.0f;
            sel += __shfl_xor(sel, 1);
            sel += __shfl_xor(sel, 2);
            sel += __shfl_xor(sel, 4);
            sel += __shfl_xor(sel, 8);
            llacc += sel - m - logf(sum);
        }
        LBAR;   // barrier2: new Xb visible, Lg consumed
    }

    if (w < 4 && (l & 15) == 0)
        out[b0 + w * 4 + (l >> 4)] = llacc;
}

extern "C" void kernel_launch(void* const* d_in, const int* in_sizes, int n_in,
                              void* d_out, int out_size, void* d_ws, size_t ws_size,
                              hipStream_t stream) {
    const float* A  = (const float*)d_in[0];   // (512,512)
    const float* B  = (const float*)d_in[1];   // (512,64)
    const float* C  = (const float*)d_in[2];   // (64,512)
    const float* Pp = (const float*)d_in[3];   // (64,512)
    const float* init = (const float*)d_in[4]; // (512,)
    const int* tokens = (const int*)d_in[5];   // (512,64)
    float* out = (float*)d_out;

    // workspace layout (needs 851,968 bytes)
    short* A16    = (short*)d_ws;                              // 512*512*2 = 524288
    short* Ceff16 = (short*)((char*)d_ws + 524288);            // 64*512*2  =  65536
    f32x2* PPB    = (f32x2*)((char*)d_ws + 589824);            // 64*512*8  = 262144

    ssm_prep<<<256, 256, 0, stream>>>(A, B, C, Pp, A16, Ceff16, PPB);
    ssm_main<<<NWG, 512, 0, stream>>>(A16, Ceff16, PPB, init, tokens, out);
}

// Round 13
// 491.793 us; speedup vs baseline: 1.2155x; 1.2155x over previous
//
#include <hip/hip_runtime.h>

#define K_DIM 512
#define S_DIM 64
#define T_LEN 64
#define BW    16      // sequences per workgroup
#define NWG   32      // 32 workgroups x 16 seqs = 512

typedef float f32x4 __attribute__((ext_vector_type(4)));
typedef float f32x2 __attribute__((ext_vector_type(2)));
typedef short bf16x8 __attribute__((ext_vector_type(8)));

__device__ __forceinline__ short f2bf(float f) {
    unsigned u = __builtin_bit_cast(unsigned, f);
    u += 0x7fffu + ((u >> 16) & 1u);   // round-to-nearest-even
    return (short)(u >> 16);
}

// ---------------- pre-pass: bf16 A/Ceff + packed {pi, pi*Bt} pairs ----------------
__global__ void ssm_prep(const float* __restrict__ A, const float* __restrict__ B,
                         const float* __restrict__ C, const float* __restrict__ Pp,
                         short* __restrict__ A16, short* __restrict__ Ceff16,
                         f32x2* __restrict__ PPB) {
    int i = blockIdx.x * blockDim.x + threadIdx.x;
    int stride = gridDim.x * blockDim.x;
    for (int idx = i; idx < K_DIM * K_DIM; idx += stride)
        A16[idx] = f2bf(A[idx]);
    for (int idx = i; idx < S_DIM * K_DIM; idx += stride) {
        int s = idx >> 9;               // K_DIM == 512
        int k = idx & (K_DIM - 1);
        float p = 1.0f / (1.0f + expf(-Pp[idx]));
        Ceff16[idx] = f2bf(C[idx] * p);
        PPB[idx] = (f32x2){p, p * B[k * S_DIM + s]};   // {pi, pi*Bt[tok][k]}
    }
}

#define MFMA_(xa, fb, acc) acc = __builtin_amdgcn_mfma_f32_16x16x32_bf16(xa, fb, acc, 0, 0, 0)

// stream slice s (32-wide k-chunk, 4 nt-quarters) into block-scope SSA temps
#define LOADS4(s) \
    bf16x8 fa_##s = *(const bf16x8*)(aP0 + (s) * 32); \
    bf16x8 fb_##s = *(const bf16x8*)(aP1 + (s) * 32); \
    bf16x8 fc_##s = *(const bf16x8*)(aP2 + (s) * 32); \
    bf16x8 fd_##s = *(const bf16x8*)(aP3 + (s) * 32);

#define COMPS4(s) { \
    bf16x8 xa = *(const bf16x8*)&Xb[p][lr][(s) * 32 + 8 * lg]; \
    MFMA_(xa, fa_##s, acc0); MFMA_(xa, fb_##s, acc1); \
    MFMA_(xa, fc_##s, acc2); MFMA_(xa, fd_##s, acc3); }

// raw barrier: drain LDS ops only; wave-private vmem loads ride across
#define LBAR asm volatile("s_waitcnt lgkmcnt(0)\ns_barrier" ::: "memory")

// ---------------- main: 32 WGs x 512 threads (8 waves), 16 seqs/WG, 64 steps ----------------
// Single barrier per step: Xb parity double-buffer (read p, write 1-p), Lg
// parity x K-half buffers, softmax deferred one step (reads Lg[1-p][0..1]).
// R12 bug fixed: Lg keeps its K-half dimension -- waves 0-3 (kh=0) and 4-7
// (kh=1) write DISTINCT partials which the softmax sums.
__global__ __launch_bounds__(512) __attribute__((amdgpu_waves_per_eu(2, 2)))
void ssm_main(
    const short* __restrict__ A16,     // [K][K] bf16 row-major
    const short* __restrict__ Ceff16,  // [S][K] bf16
    const f32x2* __restrict__ PPB,     // [S][K] {pi, pi*Bt}
    const float* __restrict__ init,    // [K]
    const int*   __restrict__ tokens,  // [BSZ][T]
    float*       __restrict__ out)     // [BSZ]
{
    __shared__ short Xb[2][BW][520];        // 33.3 KB bf16 state, parity buffers
    __shared__ short Cb[S_DIM][520];        // 66.6 KB Ceff (step-invariant, staged once)
    __shared__ float Lg[2][2][BW][68];      // 17.4 KB logits partials: parity x K-half
    __shared__ int   tokS[BW][T_LEN];       //  4.1 KB   (total ~121 KB -> 1 WG/CU)

    const int tid = threadIdx.x;
    const int w  = tid >> 6;     // wave 0..7, owns k-range [w*64, w*64+64)
    const int l  = tid & 63;
    const int lg = l >> 4;
    const int lr = l & 15;
    const int b0 = blockIdx.x * BW;

    for (int idx = tid; idx < BW * T_LEN; idx += 512) {
        int r = idx >> 6, t = idx & 63;
        tokS[r][t] = tokens[(b0 + r) * T_LEN + t];
    }
    for (int idx = tid; idx < BW * K_DIM; idx += 512) {
        int r = idx >> 9, k = idx & (K_DIM - 1);
        Xb[0][r][k] = f2bf(init[k]);
    }
    for (int idx = tid; idx < (S_DIM * K_DIM) / 8; idx += 512) {
        int r = idx >> 6, c8 = (idx & 63) * 8;
        *(bf16x8*)&Cb[r][c8] = *(const bf16x8*)(Ceff16 + r * K_DIM + c8);
    }
    // fp32 master state: xm[nt][e] = x[seq=4*lg+e][k = w*64 + nt*16 + lr]
    float xm[4][4];
    #pragma unroll
    for (int nt = 0; nt < 4; ++nt) {
        float iv = init[w * 64 + nt * 16 + lr];
        #pragma unroll
        for (int e = 0; e < 4; ++e) xm[nt][e] = iv;
    }

    const int sq = w & 3;    // logits s-tile
    const int kh = w >> 2;   // logits K-half

    // per-lane A-fragment bases (one per nt-quarter of the wave's 64 rows)
    const short* aP0 = A16 + (w * 64 +      lr) * K_DIM + 8 * lg;
    const short* aP1 = A16 + (w * 64 + 16 + lr) * K_DIM + 8 * lg;
    const short* aP2 = A16 + (w * 64 + 32 + lr) * K_DIM + 8 * lg;
    const short* aP3 = A16 + (w * 64 + 48 + lr) * K_DIM + 8 * lg;

    float llacc = 0.0f;
    __syncthreads();

    for (int t = 0; t < T_LEN; ++t) {
        const int p = t & 1;

        // ---- prime 3 slices; their L2 latency hides under P1
        LOADS4(0) LOADS4(1) LOADS4(2)

        // ---- P1: logits partial GEMM (K-half kh), pure-LDS operands
        f32x4 lga = {0.f, 0.f, 0.f, 0.f};
        #pragma unroll
        for (int i = 0; i < 8; ++i) {
            bf16x8 xa = *(const bf16x8*)&Xb[p][lr][kh * 256 + i * 32 + 8 * lg];
            bf16x8 cb = *(const bf16x8*)&Cb[sq * 16 + lr][kh * 256 + i * 32 + 8 * lg];
            MFMA_(xa, cb, lga);
        }
        #pragma unroll
        for (int e = 0; e < 4; ++e)
            Lg[p][kh][4 * lg + e][sq * 16 + lr] = lga[e];

        // ---- P2: update GEMM, depth-3 slice pipeline, pure VGPR streaming
        f32x4 acc0 = {0.f, 0.f, 0.f, 0.f};
        f32x4 acc1 = {0.f, 0.f, 0.f, 0.f};
        f32x4 acc2 = {0.f, 0.f, 0.f, 0.f};
        f32x4 acc3 = {0.f, 0.f, 0.f, 0.f};
        COMPS4(0)  LOADS4(3)
        COMPS4(1)  LOADS4(4)
        COMPS4(2)  LOADS4(5)
        COMPS4(3)  LOADS4(6)
        COMPS4(4)  LOADS4(7)
        COMPS4(5)  LOADS4(8)
        COMPS4(6)  LOADS4(9)
        COMPS4(7)  LOADS4(10)
        COMPS4(8)  LOADS4(11)
        COMPS4(9)  LOADS4(12)
        COMPS4(10) LOADS4(13)
        COMPS4(11) LOADS4(14)
        COMPS4(12) LOADS4(15)
        COMPS4(13)
        COMPS4(14)
        // ---- gating gathers: only slice 15 (16 regs) in flight here -> low peak
        int mytok[4];
        #pragma unroll
        for (int e = 0; e < 4; ++e) mytok[e] = tokS[4 * lg + e][t];
        f32x2 ppv[4][4];
        #pragma unroll
        for (int nt = 0; nt < 4; ++nt) {
            int k = w * 64 + nt * 16 + lr;
            #pragma unroll
            for (int e = 0; e < 4; ++e)
                ppv[nt][e] = PPB[mytok[e] * K_DIM + k];
        }
        COMPS4(15)

        // ---- P3: gating in fp32, write Xb[1-p] (no WAR with readers of Xb[p])
        #pragma unroll
        for (int nt = 0; nt < 4; ++nt) {
            int k = w * 64 + nt * 16 + lr;
            #pragma unroll
            for (int e = 0; e < 4; ++e) {
                float a  = (nt == 0) ? acc0[e] : (nt == 1) ? acc1[e]
                         : (nt == 2) ? acc2[e] : acc3[e];
                float nx = xm[nt][e] + ppv[nt][e][0] * (a - xm[nt][e]) + ppv[nt][e][1];
                xm[nt][e] = nx;
                Xb[1 - p][4 * lg + e][k] = f2bf(nx);
            }
        }
        // ---- deferred softmax: step t-1 logits = Lg[1-p][0] + Lg[1-p][1]
        if (t > 0 && w < 4) {
            int b = w * 4 + (l >> 4);
            int i = l & 15;
            float v[4];
            #pragma unroll
            for (int c = 0; c < 4; ++c)
                v[c] = Lg[1 - p][0][b][i * 4 + c] + Lg[1 - p][1][b][i * 4 + c];
            float m = fmaxf(fmaxf(v[0], v[1]), fmaxf(v[2], v[3]));
            m = fmaxf(m, __shfl_xor(m, 1));
            m = fmaxf(m, __shfl_xor(m, 2));
            m = fmaxf(m, __shfl_xor(m, 4));
            m = fmaxf(m, __shfl_xor(m, 8));
            float sum = expf(v[0] - m) + expf(v[1] - m) + expf(v[2] - m) + expf(v[3] - m);
            sum += __shfl_xor(sum, 1);
            sum += __shfl_xor(sum, 2);
            sum += __shfl_xor(sum, 4);
            sum += __shfl_xor(sum, 8);
            int tok = tokS[b][t - 1];
            float sel = (i == (tok >> 2)) ? v[tok & 3] : 0.0f;
            sel += __shfl_xor(sel, 1);
            sel += __shfl_xor(sel, 2);
            sel += __shfl_xor(sel, 4);
            sel += __shfl_xor(sel, 8);
            llacc += sel - m - logf(sum);
        }
        LBAR;   // single barrier: Xb[1-p] + Lg[p] visible for next step
    }

    // epilogue: softmax for the last step (t = 63, parity 1 -> Lg[1][*])
    if (w < 4) {
        int b = w * 4 + (l >> 4);
        int i = l & 15;
        float v[4];
        #pragma unroll
        for (int c = 0; c < 4; ++c)
            v[c] = Lg[1][0][b][i * 4 + c] + Lg[1][1][b][i * 4 + c];
        float m = fmaxf(fmaxf(v[0], v[1]), fmaxf(v[2], v[3]));
        m = fmaxf(m, __shfl_xor(m, 1));
        m = fmaxf(m, __shfl_xor(m, 2));
        m = fmaxf(m, __shfl_xor(m, 4));
        m = fmaxf(m, __shfl_xor(m, 8));
        float sum = expf(v[0] - m) + expf(v[1] - m) + expf(v[2] - m) + expf(v[3] - m);
        sum += __shfl_xor(sum, 1);
        sum += __shfl_xor(sum, 2);
        sum += __shfl_xor(sum, 4);
        sum += __shfl_xor(sum, 8);
        int tok = tokS[b][T_LEN - 1];
        float sel = (i == (tok >> 2)) ? v[tok & 3] : 0.0f;
        sel += __shfl_xor(sel, 1);
        sel += __shfl_xor(sel, 2);
        sel += __shfl_xor(sel, 4);
        sel += __shfl_xor(sel, 8);
        llacc += sel - m - logf(sum);

        if ((l & 15) == 0)
            out[b0 + w * 4 + (l >> 4)] = llacc;
    }
}

extern "C" void kernel_launch(void* const* d_in, const int* in_sizes, int n_in,
                              void* d_out, int out_size, void* d_ws, size_t ws_size,
                              hipStream_t stream) {
    const float* A  = (const float*)d_in[0];   // (512,512)
    const float* B  = (const float*)d_in[1];   // (512,64)
    const float* C  = (const float*)d_in[2];   // (64,512)
    const float* Pp = (const float*)d_in[3];   // (64,512)
    const float* init = (const float*)d_in[4]; // (512,)
    const int* tokens = (const int*)d_in[5];   // (512,64)
    float* out = (float*)d_out;

    // workspace layout (needs 851,968 bytes)
    short* A16    = (short*)d_ws;                              // 512*512*2 = 524288
    short* Ceff16 = (short*)((char*)d_ws + 524288);            // 64*512*2  =  65536
    f32x2* PPB    = (f32x2*)((char*)d_ws + 589824);            // 64*512*8  = 262144

    ssm_prep<<<256, 256, 0, stream>>>(A, B, C, Pp, A16, Ceff16, PPB);
    ssm_main<<<NWG, 512, 0, stream>>>(A16, Ceff16, PPB, init, tokens, out);
}

// Round 15
// 356.377 us; speedup vs baseline: 1.6774x; 1.3800x over previous
//
#include <hip/hip_runtime.h>

#define K_DIM 512
#define S_DIM 64
#define T_LEN 64
#define BW    16      // sequences per workgroup
#define NWG   32      // 32 workgroups x 16 seqs = 512

typedef float f32x4 __attribute__((ext_vector_type(4)));
typedef float f32x2 __attribute__((ext_vector_type(2)));
typedef short bf16x8 __attribute__((ext_vector_type(8)));

__device__ __forceinline__ short f2bf(float f) {
    unsigned u = __builtin_bit_cast(unsigned, f);
    u += 0x7fffu + ((u >> 16) & 1u);   // round-to-nearest-even
    return (short)(u >> 16);
}

// ---------------- pre-pass: bf16 A/Ceff + packed {pi, pi*Bt} pairs ----------------
__global__ void ssm_prep(const float* __restrict__ A, const float* __restrict__ B,
                         const float* __restrict__ C, const float* __restrict__ Pp,
                         short* __restrict__ A16, short* __restrict__ Ceff16,
                         f32x2* __restrict__ PPB) {
    int i = blockIdx.x * blockDim.x + threadIdx.x;
    int stride = gridDim.x * blockDim.x;
    for (int idx = i; idx < K_DIM * K_DIM; idx += stride)
        A16[idx] = f2bf(A[idx]);
    for (int idx = i; idx < S_DIM * K_DIM; idx += stride) {
        int s = idx >> 9;               // K_DIM == 512
        int k = idx & (K_DIM - 1);
        float p = 1.0f / (1.0f + expf(-Pp[idx]));
        Ceff16[idx] = f2bf(C[idx] * p);
        PPB[idx] = (f32x2){p, p * B[k * S_DIM + s]};   // {pi, pi*Bt[tok][k]}
    }
}

#define MFMA_(xa, fb, acc) acc = __builtin_amdgcn_mfma_f32_16x16x32_bf16(xa, fb, acc, 0, 0, 0)

// stream slice s (32-wide k-chunk, 4 nt-quarters) into block-scope SSA temps
#define LOADS4(s) \
    bf16x8 fa_##s = *(const bf16x8*)(aP0 + (s) * 32); \
    bf16x8 fb_##s = *(const bf16x8*)(aP1 + (s) * 32); \
    bf16x8 fc_##s = *(const bf16x8*)(aP2 + (s) * 32); \
    bf16x8 fd_##s = *(const bf16x8*)(aP3 + (s) * 32);

#define COMPS4(s) { \
    bf16x8 xa = *(const bf16x8*)&Xb[lr][(s) * 32 + 8 * lg]; \
    MFMA_(xa, fa_##s, acc0); MFMA_(xa, fb_##s, acc1); \
    MFMA_(xa, fc_##s, acc2); MFMA_(xa, fd_##s, acc3); }

// consume LDS-resident slice G (12..15): lane l's 16B fragment at Aq[w][G-12][nt][l]
// (R14 bug: used &Aq[w][G-12][0][l*8] which indexes the [64] dim by l*8 -> byte
// offset 128*l instead of 16*l -> OOB garbage for l>=8 -> NaN. Fixed: [nt][l][0].)
#define COMPSL(G) { \
    bf16x8 xa = *(const bf16x8*)&Xb[lr][(G) * 32 + 8 * lg]; \
    bf16x8 f0 = *(const bf16x8*)&Aq[w][(G) - 12][0][l][0]; \
    bf16x8 f1 = *(const bf16x8*)&Aq[w][(G) - 12][1][l][0]; \
    bf16x8 f2 = *(const bf16x8*)&Aq[w][(G) - 12][2][l][0]; \
    bf16x8 f3 = *(const bf16x8*)&Aq[w][(G) - 12][3][l][0]; \
    MFMA_(xa, f0, acc0); MFMA_(xa, f1, acc1); \
    MFMA_(xa, f2, acc2); MFMA_(xa, f3, acc3); }

// raw barrier: drain LDS ops only; wave-private vmem loads ride across
#define LBAR asm volatile("s_waitcnt lgkmcnt(0)\ns_barrier" ::: "memory")

// ---------------- main: 32 WGs x 512 threads (8 waves), 16 seqs/WG, 64 steps ----------------
// A-columns 384..512 (4 slices, 128 KB) LDS-resident in fragment order (staged
// once); slices 0..11 streamed depth-2 through VGPRs; Ceff re-read from L2
// (step-invariant addresses, L2-hot). Peak VGPR live-set ~94-110 < 128.
__global__ __launch_bounds__(512) __attribute__((amdgpu_waves_per_eu(2, 2)))
void ssm_main(
    const short* __restrict__ A16,     // [K][K] bf16 row-major
    const short* __restrict__ Ceff16,  // [S][K] bf16
    const f32x2* __restrict__ PPB,     // [S][K] {pi, pi*Bt}
    const float* __restrict__ init,    // [K]
    const int*   __restrict__ tokens,  // [BSZ][T]
    float*       __restrict__ out)     // [BSZ]
{
    __shared__ short Aq[8][4][4][64][8];    // 128 KB: A cols 384..512, fragment order
    __shared__ short Xb[BW][520];           // 16.6 KB bf16 state
    __shared__ float Lg[2][BW][68];         //  8.7 KB logits partials (2 K-halves)
    __shared__ int   tokS[BW][T_LEN];       //  4.1 KB   (total 160,512 B -> 1 WG/CU)

    const int tid = threadIdx.x;
    const int w  = tid >> 6;     // wave 0..7, owns k-range [w*64, w*64+64)
    const int l  = tid & 63;
    const int lg = l >> 4;
    const int lr = l & 15;
    const int b0 = blockIdx.x * BW;

    for (int idx = tid; idx < BW * T_LEN; idx += 512) {
        int r = idx >> 6, t = idx & 63;
        tokS[r][t] = tokens[(b0 + r) * T_LEN + t];
    }
    for (int idx = tid; idx < BW * K_DIM; idx += 512) {
        int r = idx >> 9, k = idx & (K_DIM - 1);
        Xb[r][k] = f2bf(init[k]);
    }
    // stage A columns 384..512 into LDS in fragment order (once; reused 64 steps)
    for (int idx = tid; idx < 8192; idx += 512) {
        int w2 = idx >> 10, rem = idx & 1023;
        int s2 = rem >> 8, nt2 = (rem >> 6) & 3, l2 = rem & 63;
        *(bf16x8*)&Aq[w2][s2][nt2][l2][0] =
            *(const bf16x8*)(A16 + (w2 * 64 + nt2 * 16 + (l2 & 15)) * K_DIM
                             + (12 + s2) * 32 + (l2 >> 4) * 8);
    }
    // fp32 master state: xm[nt][e] = x[seq=4*lg+e][k = w*64 + nt*16 + lr]
    float xm[4][4];
    #pragma unroll
    for (int nt = 0; nt < 4; ++nt) {
        float iv = init[w * 64 + nt * 16 + lr];
        #pragma unroll
        for (int e = 0; e < 4; ++e) xm[nt][e] = iv;
    }

    const int sq = w & 3;    // logits s-tile
    const int kh = w >> 2;   // logits K-half

    // per-lane A-fragment bases (one per nt-quarter of the wave's 64 rows)
    const short* aP0 = A16 + (w * 64 +      lr) * K_DIM + 8 * lg;
    const short* aP1 = A16 + (w * 64 + 16 + lr) * K_DIM + 8 * lg;
    const short* aP2 = A16 + (w * 64 + 32 + lr) * K_DIM + 8 * lg;
    const short* aP3 = A16 + (w * 64 + 48 + lr) * K_DIM + 8 * lg;
    const short* cP  = Ceff16 + (sq * 16 + lr) * K_DIM + kh * 256 + 8 * lg;

    float llacc = 0.0f;
    __syncthreads();

    for (int t = 0; t < T_LEN; ++t) {
        // ---- prime 2 A-slices; latency hides under P1
        LOADS4(0) LOADS4(1)

        // ---- P1: logits partial GEMM (K-half kh); cb from L2 (step-invariant, hot)
        f32x4 lga = {0.f, 0.f, 0.f, 0.f};
        #pragma unroll
        for (int i = 0; i < 8; ++i) {
            bf16x8 cb = *(const bf16x8*)(cP + i * 32);
            bf16x8 xa = *(const bf16x8*)&Xb[lr][kh * 256 + i * 32 + 8 * lg];
            MFMA_(xa, cb, lga);
        }
        #pragma unroll
        for (int e = 0; e < 4; ++e)
            Lg[kh][4 * lg + e][sq * 16 + lr] = lga[e];

        // ---- P2: slices 0..11 depth-2 VGPR stream
        f32x4 acc0 = {0.f, 0.f, 0.f, 0.f};
        f32x4 acc1 = {0.f, 0.f, 0.f, 0.f};
        f32x4 acc2 = {0.f, 0.f, 0.f, 0.f};
        f32x4 acc3 = {0.f, 0.f, 0.f, 0.f};
        COMPS4(0)  LOADS4(2)
        COMPS4(1)  LOADS4(3)
        COMPS4(2)  LOADS4(4)
        COMPS4(3)  LOADS4(5)
        COMPS4(4)  LOADS4(6)
        COMPS4(5)  LOADS4(7)
        COMPS4(6)  LOADS4(8)
        COMPS4(7)  LOADS4(9)
        COMPS4(8)  LOADS4(10)
        COMPS4(9)  LOADS4(11)
        COMPS4(10)
        COMPS4(11)
        // ---- gating gathers: zero A-loads in flight; latency hides under LDS tail
        int mytok[4];
        #pragma unroll
        for (int e = 0; e < 4; ++e) mytok[e] = tokS[4 * lg + e][t];
        f32x2 ppv[4][4];
        #pragma unroll
        for (int nt = 0; nt < 4; ++nt) {
            int k = w * 64 + nt * 16 + lr;
            #pragma unroll
            for (int e = 0; e < 4; ++e)
                ppv[nt][e] = PPB[mytok[e] * K_DIM + k];
        }
        // ---- slices 12..15 from LDS (zero vmem)
        COMPSL(12) COMPSL(13) COMPSL(14) COMPSL(15)
        LBAR;   // barrier1: Xb reads done, Lg visible

        // ---- P3: gating in fp32, rewrite Xb
        #pragma unroll
        for (int nt = 0; nt < 4; ++nt) {
            int k = w * 64 + nt * 16 + lr;
            #pragma unroll
            for (int e = 0; e < 4; ++e) {
                float a  = (nt == 0) ? acc0[e] : (nt == 1) ? acc1[e]
                         : (nt == 2) ? acc2[e] : acc3[e];
                float nx = xm[nt][e] + ppv[nt][e][0] * (a - xm[nt][e]) + ppv[nt][e][1];
                xm[nt][e] = nx;
                Xb[4 * lg + e][k] = f2bf(nx);
            }
        }
        // waves 0..3: log-softmax + LL for 4 seqs each (16 lanes/seq, 4 logits/lane)
        if (w < 4) {
            int b = w * 4 + (l >> 4);
            int i = l & 15;
            float v[4];
            #pragma unroll
            for (int c = 0; c < 4; ++c)
                v[c] = Lg[0][b][i * 4 + c] + Lg[1][b][i * 4 + c];
            float m = fmaxf(fmaxf(v[0], v[1]), fmaxf(v[2], v[3]));
            m = fmaxf(m, __shfl_xor(m, 1));
            m = fmaxf(m, __shfl_xor(m, 2));
            m = fmaxf(m, __shfl_xor(m, 4));
            m = fmaxf(m, __shfl_xor(m, 8));
            float sum = expf(v[0] - m) + expf(v[1] - m) + expf(v[2] - m) + expf(v[3] - m);
            sum += __shfl_xor(sum, 1);
            sum += __shfl_xor(sum, 2);
            sum += __shfl_xor(sum, 4);
            sum += __shfl_xor(sum, 8);
            int tok = tokS[b][t];
            float sel = (i == (tok >> 2)) ? v[tok & 3] : 0.0f;
            sel += __shfl_xor(sel, 1);
            sel += __shfl_xor(sel, 2);
            sel += __shfl_xor(sel, 4);
            sel += __shfl_xor(sel, 8);
            llacc += sel - m - logf(sum);
        }
        LBAR;   // barrier2: new Xb visible, Lg consumed
    }

    if (w < 4 && (l & 15) == 0)
        out[b0 + w * 4 + (l >> 4)] = llacc;
}

extern "C" void kernel_launch(void* const* d_in, const int* in_sizes, int n_in,
                              void* d_out, int out_size, void* d_ws, size_t ws_size,
                              hipStream_t stream) {
    const float* A  = (const float*)d_in[0];   // (512,512)
    const float* B  = (const float*)d_in[1];   // (512,64)
    const float* C  = (const float*)d_in[2];   // (64,512)
    const float* Pp = (const float*)d_in[3];   // (64,512)
    const float* init = (const float*)d_in[4]; // (512,)
    const int* tokens = (const int*)d_in[5];   // (512,64)
    float* out = (float*)d_out;

    // workspace layout (needs 851,968 bytes)
    short* A16    = (short*)d_ws;                              // 512*512*2 = 524288
    short* Ceff16 = (short*)((char*)d_ws + 524288);            // 64*512*2  =  65536
    f32x2* PPB    = (f32x2*)((char*)d_ws + 589824);            // 64*512*8  = 262144

    ssm_prep<<<256, 256, 0, stream>>>(A, B, C, Pp, A16, Ceff16, PPB);
    ssm_main<<<NWG, 512, 0, stream>>>(A16, Ceff16, PPB, init, tokens, out);
}